// Round 3
// baseline (535.769 us; speedup 1.0000x reference)
//
#include <hip/hip_runtime.h>
#include <math.h>

// Shapes fixed by reference: B=8, K=8, C=256, H=W=64 -> HW=4096 = 1024 float4/plane.
#define B_DIM 8
#define K_DIM 8
#define C_DIM 256
#define HW4   1024                 // float4 per (b,k,c) plane
#define BC    (B_DIM * C_DIM)      // 2048
#define BKC   (B_DIM * K_DIM * C_DIM)  // 16384

// ---------------- Kernel 1: per-(b,k,c) dot & sumsq reduction ----------------
// One 256-thread block per (b,k,c) plane. Thread t loads 4 independent float4
// of CR and CT each, reduces via wave shuffle + LDS, writes dot/ss to ws.
__global__ __launch_bounds__(256)
void dfs_reduce(const float4* __restrict__ CR,
                const float4* __restrict__ CT,
                float* __restrict__ ws_dot,   // [B*K*C]
                float* __restrict__ ws_ss)    // [B*K*C]
{
    const int bid = blockIdx.x;            // b*K*C + k*C + c
    const int b   = bid >> 11;             // / (K*C)
    const int kc  = bid & 2047;
    const int c   = kc & 255;
    const int t   = threadIdx.x;

    const int cr_base = bid * HW4;                 // CR plane
    const int ct_base = (b * C_DIM + c) * HW4;     // CT plane

    float d = 0.f, s = 0.f;
#pragma unroll
    for (int i = 0; i < 4; ++i) {
        const int off = t + i * 256;
        float4 cr = CR[cr_base + off];
        float4 ct = CT[ct_base + off];
        d = fmaf(ct.x, cr.x, d); d = fmaf(ct.y, cr.y, d);
        d = fmaf(ct.z, cr.z, d); d = fmaf(ct.w, cr.w, d);
        s = fmaf(cr.x, cr.x, s); s = fmaf(cr.y, cr.y, s);
        s = fmaf(cr.z, cr.z, s); s = fmaf(cr.w, cr.w, s);
    }
#pragma unroll
    for (int off = 32; off >= 1; off >>= 1) {
        d += __shfl_xor(d, off, 64);
        s += __shfl_xor(s, off, 64);
    }
    __shared__ float rd[4], rs[4];
    const int wave = t >> 6, lane = t & 63;
    if (lane == 0) { rd[wave] = d; rs[wave] = s; }
    __syncthreads();
    if (t == 0) {
        ws_dot[bid] = rd[0] + rd[1] + rd[2] + rd[3];
        ws_ss[bid]  = rs[0] + rs[1] + rs[2] + rs[3];
    }
}

// ---------------- Kernel 2: softmax over K per (b,c) ----------------
// 2048 threads total; thread handles one (b,c): reads 8 dot + 8 ss, writes 8 w.
__global__ __launch_bounds__(256)
void dfs_softmax(const float* __restrict__ ws_dot,
                 const float* __restrict__ ws_ss,
                 float* __restrict__ ws_w)    // [B*K*C], same (b,k,c) layout
{
    const int idx = blockIdx.x * 256 + threadIdx.x;   // b*C + c
    if (idx >= BC) return;
    const int b = idx >> 8, c = idx & 255;

    float sim[K_DIM];
    float m = -1e30f;
#pragma unroll
    for (int k = 0; k < K_DIM; ++k) {
        const int p = (b * K_DIM + k) * C_DIM + c;
        float dd = ws_dot[p];
        float ss = ws_ss[p];
        sim[k] = 2.0f * dd / sqrtf(ss);
        m = fmaxf(m, sim[k]);
    }
    float sum = 0.f;
#pragma unroll
    for (int k = 0; k < K_DIM; ++k) { sim[k] = expf(sim[k] - m); sum += sim[k]; }
    const float inv = 1.0f / sum;
#pragma unroll
    for (int k = 0; k < K_DIM; ++k)
        ws_w[(b * K_DIM + k) * C_DIM + c] = sim[k] * inv;
}

// ---------------- Kernel 3: weighted mix of IR ----------------
// 8192 blocks x 256 threads; block handles a quarter-plane of one (b,c).
__global__ __launch_bounds__(256)
void dfs_mix(const float4* __restrict__ IR,
             const float* __restrict__ ws_w,
             float4* __restrict__ out)
{
    const int bid   = blockIdx.x;          // (b*C + c) * 4 + q
    const int q     = bid & 3;
    const int bc    = bid >> 2;            // b*C + c
    const int b     = bc >> 8, c = bc & 255;
    const int t     = threadIdx.x;
    const int off   = q * 256 + t;         // 0..1023 within plane

    __shared__ float w[K_DIM];
    if (t < K_DIM) w[t] = ws_w[(b * K_DIM + t) * C_DIM + c];
    __syncthreads();

    const int plane0 = (b * (K_DIM * C_DIM) + c) * HW4 + off;   // k=0
    float4 acc = make_float4(0.f, 0.f, 0.f, 0.f);
#pragma unroll
    for (int k = 0; k < K_DIM; ++k) {
        float4 v = IR[plane0 + k * (C_DIM * HW4)];
        const float wk = w[k];
        acc.x = fmaf(wk, v.x, acc.x);
        acc.y = fmaf(wk, v.y, acc.y);
        acc.z = fmaf(wk, v.z, acc.z);
        acc.w = fmaf(wk, v.w, acc.w);
    }
    out[bc * HW4 + off] = acc;
}

extern "C" void kernel_launch(void* const* d_in, const int* in_sizes, int n_in,
                              void* d_out, int out_size, void* d_ws, size_t ws_size,
                              hipStream_t stream) {
    const float4* IR = (const float4*)d_in[0];
    const float4* CR = (const float4*)d_in[1];
    const float4* CT = (const float4*)d_in[2];
    float4* out      = (float4*)d_out;

    float* ws_dot = (float*)d_ws;            // 16384 floats
    float* ws_ss  = ws_dot + BKC;            // 16384 floats
    float* ws_w   = ws_ss + BKC;             // 16384 floats  (total 192 KB)

    dfs_reduce <<<BKC,     256, 0, stream>>>(CR, CT, ws_dot, ws_ss);
    dfs_softmax<<<BC / 256,256, 0, stream>>>(ws_dot, ws_ss, ws_w);
    dfs_mix    <<<BC * 4,  256, 0, stream>>>(IR, ws_w, out);
}